// Round 3
// baseline (125.014 us; speedup 1.0000x reference)
//
#include <hip/hip_runtime.h>
#include <math.h>

// SPDNet fused: x[4096,64,256] --(bf16 rn-split MFMA)--> V^T = x^T W
//   --> Y = V V^T/T - m m^T  (32x32 SPD, C-layout regs)
//   --> log(Y) via Chebyshev matrix recurrence on MFMA (in-register,
//       C->B frag conversion via permlane32_swap; no LDS anywhere)
//   --> <Wc_o, log(Y)> + bc --> log_softmax --> out.
// One wave per sample; 4 waves/block; __launch_bounds__(256,4) -> 4 waves/SIMD.

typedef __attribute__((ext_vector_type(8))) short short8;   // bf16x8 frag (4 VGPR)
typedef __attribute__((ext_vector_type(16))) float f32x16;  // MFMA C/D

#define NCH 18

__device__ inline unsigned cvt_pk_bf16(float a, float b) {
  // dst.lo16 = bf16_rn(a), dst.hi16 = bf16_rn(b)
  unsigned r;
  asm("v_cvt_pk_bf16_f32 %0, %1, %2" : "=v"(r) : "v"(a), "v"(b));
  return r;
}
// rn-split: hp = packed bf16(a,b); lp = packed bf16 of residuals
__device__ inline void split_pair(float a, float b, unsigned& hp, unsigned& lp) {
  hp = cvt_pk_bf16(a, b);
  const float ha = __builtin_bit_cast(float, hp << 16);
  const float hb = __builtin_bit_cast(float, hp & 0xffff0000u);
  lp = cvt_pk_bf16(a - ha, b - hb);
}

// C-layout (lane holds col=l&31, rows (m&3)+8*(m>>2)+4*(l>>5)) -> B-frag pairs
// for the two K=16 slices, hi/lo bf16 split. B-frag: lane holds
// M[ks*16 + 8*(l>>5) + jj][l&31], jj=0..7 (also A-frag of M for symmetric M).
__device__ inline void c2frags(const float* c, short8& h0, short8& l0,
                               short8& h1, short8& l1) {
  unsigned ph[8], pl[8];
#pragma unroll
  for (int w = 0; w < 8; ++w) split_pair(c[2 * w], c[2 * w + 1], ph[w], pl[w]);
  union { unsigned u[4]; short8 s; } H0, L0, H1, L1;
  {
    auto r = __builtin_amdgcn_permlane32_swap((int)ph[0], (int)ph[2], false, false);
    H0.u[0] = (unsigned)r[0]; H0.u[2] = (unsigned)r[1];
    r = __builtin_amdgcn_permlane32_swap((int)ph[1], (int)ph[3], false, false);
    H0.u[1] = (unsigned)r[0]; H0.u[3] = (unsigned)r[1];
    r = __builtin_amdgcn_permlane32_swap((int)ph[4], (int)ph[6], false, false);
    H1.u[0] = (unsigned)r[0]; H1.u[2] = (unsigned)r[1];
    r = __builtin_amdgcn_permlane32_swap((int)ph[5], (int)ph[7], false, false);
    H1.u[1] = (unsigned)r[0]; H1.u[3] = (unsigned)r[1];
    r = __builtin_amdgcn_permlane32_swap((int)pl[0], (int)pl[2], false, false);
    L0.u[0] = (unsigned)r[0]; L0.u[2] = (unsigned)r[1];
    r = __builtin_amdgcn_permlane32_swap((int)pl[1], (int)pl[3], false, false);
    L0.u[1] = (unsigned)r[0]; L0.u[3] = (unsigned)r[1];
    r = __builtin_amdgcn_permlane32_swap((int)pl[4], (int)pl[6], false, false);
    L1.u[0] = (unsigned)r[0]; L1.u[2] = (unsigned)r[1];
    r = __builtin_amdgcn_permlane32_swap((int)pl[5], (int)pl[7], false, false);
    L1.u[1] = (unsigned)r[0]; L1.u[3] = (unsigned)r[1];
  }
  h0 = H0.s; l0 = L0.s; h1 = H1.s; l1 = L1.s;
}

__device__ inline f32x16 mfma_bf16(short8 a, short8 b, f32x16 c) {
  return __builtin_amdgcn_mfma_f32_32x32x16_bf16(a, b, c, 0, 0, 0);
}

__global__ __launch_bounds__(256, 4) void spd_fused(
    const float* __restrict__ x, const float* __restrict__ W,
    const float* __restrict__ Wc, const float* __restrict__ bcv,
    float* __restrict__ out, int nB)
{
  const int wv = threadIdx.x >> 6;
  const int l  = threadIdx.x & 63;
  const int b  = blockIdx.x * 4 + wv;
  if (b >= nB) return;
  const int half = l >> 5, col = l & 31;

  // ---- W as B-frags (K-slices of 16 over C=64), rn-split ----
  short8 wh[4], wl[4];
#pragma unroll
  for (int cs = 0; cs < 4; ++cs) {
    float wr[8];
#pragma unroll
    for (int j = 0; j < 8; ++j)
      wr[j] = W[(cs * 16 + 8 * half + j) * 32 + col];
    union { unsigned u[4]; short8 s; } Hh, Ll;
#pragma unroll
    for (int w = 0; w < 4; ++w) split_pair(wr[2 * w], wr[2 * w + 1], Hh.u[w], Ll.u[w]);
    wh[cs] = Hh.s; wl[cs] = Ll.s;
  }

  // ---- stream x: Vtb = x_tb^T W (MFMA), Y += Vtb^T Vtb (MFMA) ----
  const float* xb = x + (size_t)b * (64 * 256);
  f32x16 Yac = {0.f,0.f,0.f,0.f,0.f,0.f,0.f,0.f,0.f,0.f,0.f,0.f,0.f,0.f,0.f,0.f};
  float macc = 0.f;

  for (int tb = 0; tb < 8; ++tb) {
    f32x16 V1 = {0.f,0.f,0.f,0.f,0.f,0.f,0.f,0.f,0.f,0.f,0.f,0.f,0.f,0.f,0.f,0.f};
    f32x16 V2 = {0.f,0.f,0.f,0.f,0.f,0.f,0.f,0.f,0.f,0.f,0.f,0.f,0.f,0.f,0.f,0.f};
#pragma unroll
    for (int cs = 0; cs < 4; ++cs) {
      float xr[8];
#pragma unroll
      for (int j = 0; j < 8; ++j)
        xr[j] = xb[(cs * 16 + 8 * half + j) * 256 + tb * 32 + col];
      union { unsigned u[4]; short8 s; } Hh, Ll;
#pragma unroll
      for (int w = 0; w < 4; ++w) split_pair(xr[2 * w], xr[2 * w + 1], Hh.u[w], Ll.u[w]);
      if (cs < 2) {
        V1 = mfma_bf16(Hh.s, wh[cs], V1);
        V1 = mfma_bf16(Hh.s, wl[cs], V1);
        V1 = mfma_bf16(Ll.s, wh[cs], V1);
      } else {
        V2 = mfma_bf16(Hh.s, wh[cs], V2);
        V2 = mfma_bf16(Hh.s, wl[cs], V2);
        V2 = mfma_bf16(Ll.s, wh[cs], V2);
      }
    }
    float vv[16];
#pragma unroll
    for (int m = 0; m < 16; ++m) { vv[m] = V1[m] + V2[m]; macc += vv[m]; }
    short8 bh0, bl0, bh1, bl1;
    c2frags(vv, bh0, bl0, bh1, bl1);
    Yac = mfma_bf16(bh0, bh0, Yac);
    Yac = mfma_bf16(bh0, bl0, Yac);
    Yac = mfma_bf16(bl0, bh0, Yac);
    Yac = mfma_bf16(bh1, bh1, Yac);
    Yac = mfma_bf16(bh1, bl1, Yac);
    Yac = mfma_bf16(bl1, bh1, Yac);
  }

  // ---- means, normalize: Yhat = (Y/256 - m m^T - p I)/q ----
  macc += __shfl_xor(macc, 32);
  const float msn = macc * (1.f / 256.f);     // m_d for d = col (all lanes)

  const float lo = 0.08f, hi = 3.0f;
  const float p = 0.5f * (hi + lo), q = 0.5f * (hi - lo), invq = 1.f / q;
  const float rr = -(p - sqrtf(lo * hi)) * invq;   // ~ -0.719
  const float c0 = logf(p / (1.f + rr * rr));

  float Tc[16], Tp[16], G[16];
#pragma unroll
  for (int m = 0; m < 16; ++m) {
    const int r = (m & 3) + 8 * (m >> 2) + 4 * half;
    const float mrow = __shfl(msn, r);
    const float yv = Yac[m] * (1.f / 256.f) - mrow * msn;
    const float yn = (yv - (r == col ? p : 0.f)) * invq;
    const float id = (r == col) ? 1.f : 0.f;
    Tc[m] = yn; Tp[m] = id;
    G[m] = c0 * id + (-2.f * rr) * yn;
  }

  // A-frags of symmetric Yhat (fixed across the recurrence)
  short8 ah0, al0, ah1, al1;
  c2frags(Tc, ah0, al0, ah1, al1);

  // ---- Chebyshev recurrence: T_new = 2 Yhat T - T_prev ----
  float rk = rr;
  for (int k = 2; k <= NCH; ++k) {
    short8 bh0, bl0, bh1, bl1;
    c2frags(Tc, bh0, bl0, bh1, bl1);
    f32x16 P = {0.f,0.f,0.f,0.f,0.f,0.f,0.f,0.f,0.f,0.f,0.f,0.f,0.f,0.f,0.f,0.f};
    P = mfma_bf16(ah0, bh0, P);
    P = mfma_bf16(ah1, bh1, P);
    P = mfma_bf16(ah0, bl0, P);
    P = mfma_bf16(ah1, bl1, P);
    P = mfma_bf16(al0, bh0, P);
    P = mfma_bf16(al1, bh1, P);
    rk *= rr;
    const float ck = -2.f * rk / (float)k;
#pragma unroll
    for (int m = 0; m < 16; ++m) {
      const float tn = 2.f * P[m] - Tp[m];
      Tp[m] = Tc[m]; Tc[m] = tn;
      G[m] = fmaf(ck, tn, G[m]);
    }
  }

  // ---- logits: S_o = <Wc_o, G>, wave-reduce, log_softmax ----
  float S[4];
#pragma unroll
  for (int o = 0; o < 4; ++o) {
    float s = 0.f;
#pragma unroll
    for (int m = 0; m < 16; ++m) {
      const int r = (m & 3) + 8 * (m >> 2) + 4 * half;
      s = fmaf(Wc[o * 1024 + r * 32 + col], G[m], s);
    }
    S[o] = s;
  }
#pragma unroll
  for (int off = 32; off >= 1; off >>= 1) {
    S[0] += __shfl_xor(S[0], off);
    S[1] += __shfl_xor(S[1], off);
    S[2] += __shfl_xor(S[2], off);
    S[3] += __shfl_xor(S[3], off);
  }
  if (l == 0) {
    const float lg0 = S[0] + bcv[0];
    const float lg1 = S[1] + bcv[1];
    const float lg2 = S[2] + bcv[2];
    const float lg3 = S[3] + bcv[3];
    const float mx = fmaxf(fmaxf(lg0, lg1), fmaxf(lg2, lg3));
    const float se = expf(lg0 - mx) + expf(lg1 - mx) +
                     expf(lg2 - mx) + expf(lg3 - mx);
    const float lse = mx + logf(se);
    *(float4*)&out[(size_t)b * 4] =
        make_float4(lg0 - lse, lg1 - lse, lg2 - lse, lg3 - lse);
  }
}

extern "C" void kernel_launch(void* const* d_in, const int* in_sizes, int n_in,
                              void* d_out, int out_size, void* d_ws, size_t ws_size,
                              hipStream_t stream)
{
  const float* x  = (const float*)d_in[0];
  const float* W  = (const float*)d_in[1];
  const float* Wc = (const float*)d_in[2];
  const float* bc = (const float*)d_in[3];
  float* out = (float*)d_out;

  const int nB = in_sizes[0] / (64 * 256);   // 4096
  const int blocks = (nB + 3) / 4;

  spd_fused<<<blocks, 256, 0, stream>>>(x, W, Wc, bc, out, nB);
}

// Round 4
// 70.911 us; speedup vs baseline: 1.7630x; 1.7630x over previous
//
#include <hip/hip_runtime.h>
#include <math.h>

// SPDNet fused, one wave per sample:
//  phase 1: Craw = sum_t x_t x_t^T via MFMA (4 32x32 blocks, x-frags dual-use
//           as A and B, loaded as float4 directly in frag layout)
//  sandwich: Cov = Craw/256 - mx mx^T;  Z = Cov*W;  Y = Z^T*W  (bf16 rn-split)
//  phase 2: log(Y) via degree-11 Chebyshev on [0.25,2.25] (r=-0.5, c0=0),
//           in-register MFMA recurrence, fully unrolled
//  epilogue: logits = <Wc_o, log(Y)> + bc -> log_softmax -> out. No LDS.

typedef __attribute__((ext_vector_type(8))) short short8;   // bf16x8 frag
typedef __attribute__((ext_vector_type(16))) float f32x16;  // MFMA C/D

#define NCH 11

__device__ inline unsigned cvt_pk_bf16(float a, float b) {
  unsigned r;
  asm("v_cvt_pk_bf16_f32 %0, %1, %2" : "=v"(r) : "v"(a), "v"(b));
  return r;
}
__device__ inline void split_pair(float a, float b, unsigned& hp, unsigned& lp) {
  hp = cvt_pk_bf16(a, b);
  const float ha = __builtin_bit_cast(float, hp << 16);
  const float hb = __builtin_bit_cast(float, hp & 0xffff0000u);
  lp = cvt_pk_bf16(a - ha, b - hb);
}
// 8 consecutive K-elements (two float4) -> hi/lo bf16 frags
__device__ inline void split8(const float4& u, const float4& v,
                              short8& h, short8& lo8) {
  union { unsigned u4[4]; short8 s; } H, L;
  split_pair(u.x, u.y, H.u4[0], L.u4[0]);
  split_pair(u.z, u.w, H.u4[1], L.u4[1]);
  split_pair(v.x, v.y, H.u4[2], L.u4[2]);
  split_pair(v.z, v.w, H.u4[3], L.u4[3]);
  h = H.s; lo8 = L.s;
}

// C-layout (lane: col=l&31, rows (m&3)+8*(m>>2)+4*(l>>5)) -> frag pairs for the
// two K=16 slices, hi/lo split. Output as A-operand == M^T, as B-operand == M.
__device__ inline void c2frags(const float* c, short8& h0, short8& l0,
                               short8& h1, short8& l1) {
  unsigned ph[8], pl[8];
#pragma unroll
  for (int w = 0; w < 8; ++w) split_pair(c[2 * w], c[2 * w + 1], ph[w], pl[w]);
  union { unsigned u[4]; short8 s; } H0, L0, H1, L1;
  {
    auto r = __builtin_amdgcn_permlane32_swap((int)ph[0], (int)ph[2], false, false);
    H0.u[0] = (unsigned)r[0]; H0.u[2] = (unsigned)r[1];
    r = __builtin_amdgcn_permlane32_swap((int)ph[1], (int)ph[3], false, false);
    H0.u[1] = (unsigned)r[0]; H0.u[3] = (unsigned)r[1];
    r = __builtin_amdgcn_permlane32_swap((int)ph[4], (int)ph[6], false, false);
    H1.u[0] = (unsigned)r[0]; H1.u[2] = (unsigned)r[1];
    r = __builtin_amdgcn_permlane32_swap((int)ph[5], (int)ph[7], false, false);
    H1.u[1] = (unsigned)r[0]; H1.u[3] = (unsigned)r[1];
    r = __builtin_amdgcn_permlane32_swap((int)pl[0], (int)pl[2], false, false);
    L0.u[0] = (unsigned)r[0]; L0.u[2] = (unsigned)r[1];
    r = __builtin_amdgcn_permlane32_swap((int)pl[1], (int)pl[3], false, false);
    L0.u[1] = (unsigned)r[0]; L0.u[3] = (unsigned)r[1];
    r = __builtin_amdgcn_permlane32_swap((int)pl[4], (int)pl[6], false, false);
    L1.u[0] = (unsigned)r[0]; L1.u[2] = (unsigned)r[1];
    r = __builtin_amdgcn_permlane32_swap((int)pl[5], (int)pl[7], false, false);
    L1.u[1] = (unsigned)r[0]; L1.u[3] = (unsigned)r[1];
  }
  h0 = H0.s; l0 = L0.s; h1 = H1.s; l1 = L1.s;
}

__device__ inline f32x16 mfma_bf16(short8 a, short8 b, f32x16 c) {
  return __builtin_amdgcn_mfma_f32_32x32x16_bf16(a, b, c, 0, 0, 0);
}
__device__ inline f32x16 zero16() {
  f32x16 z;
#pragma unroll
  for (int i = 0; i < 16; ++i) z[i] = 0.f;
  return z;
}
// W B-frag for c-slice cs (k = cs*16+8*half+j), hi/lo split
__device__ inline void loadWfrag(const float* __restrict__ W, int cs, int half,
                                 int col, short8& h, short8& l) {
  float wr[8];
#pragma unroll
  for (int j = 0; j < 8; ++j) wr[j] = W[(cs * 16 + 8 * half + j) * 32 + col];
  union { unsigned u4[4]; short8 s; } H, L;
#pragma unroll
  for (int w = 0; w < 4; ++w) split_pair(wr[2 * w], wr[2 * w + 1], H.u4[w], L.u4[w]);
  h = H.s; l = L.s;
}

__global__ __launch_bounds__(256) void spd_fused(
    const float* __restrict__ x, const float* __restrict__ W,
    const float* __restrict__ Wc, const float* __restrict__ bcv,
    float* __restrict__ out, int nB)
{
  const int wv = threadIdx.x >> 6;
  const int l  = threadIdx.x & 63;
  const int b  = blockIdx.x * 4 + wv;
  if (b >= nB) return;
  const int half = l >> 5, col = l & 31;

  // ---- phase 1: Craw blocks via MFMA, x-frags loaded as float4 ----
  const float* xb = x + (size_t)b * (64 * 256);
  const float* r0 = xb + col * 256 + 8 * half;        // channel col
  const float* r1 = r0 + 32 * 256;                    // channel 32+col

  f32x16 C00 = zero16(), C01 = zero16(), C10 = zero16(), C11 = zero16();
  float macc0 = 0.f, macc1 = 0.f;

  for (int tb = 0; tb < 8; ++tb) {
    const float* pa = r0 + tb * 32;
    const float4 a0 = *(const float4*)(pa);
    const float4 a1 = *(const float4*)(pa + 4);
    const float4 a2 = *(const float4*)(pa + 16);
    const float4 a3 = *(const float4*)(pa + 20);
    const float* pb = r1 + tb * 32;
    const float4 b0 = *(const float4*)(pb);
    const float4 b1 = *(const float4*)(pb + 4);
    const float4 b2 = *(const float4*)(pb + 16);
    const float4 b3 = *(const float4*)(pb + 20);

    macc0 += (a0.x + a0.y + a0.z + a0.w) + (a1.x + a1.y + a1.z + a1.w) +
             (a2.x + a2.y + a2.z + a2.w) + (a3.x + a3.y + a3.z + a3.w);
    macc1 += (b0.x + b0.y + b0.z + b0.w) + (b1.x + b1.y + b1.z + b1.w) +
             (b2.x + b2.y + b2.z + b2.w) + (b3.x + b3.y + b3.z + b3.w);

    short8 A0h, A0l, A1h, A1l, B0h, B0l, B1h, B1l;
    split8(a0, a1, A0h, A0l);  split8(a2, a3, A1h, A1l);
    split8(b0, b1, B0h, B0l);  split8(b2, b3, B1h, B1l);

    // ks0
    C00 = mfma_bf16(A0h, A0h, C00); C00 = mfma_bf16(A0h, A0l, C00); C00 = mfma_bf16(A0l, A0h, C00);
    C01 = mfma_bf16(A0h, B0h, C01); C01 = mfma_bf16(A0h, B0l, C01); C01 = mfma_bf16(A0l, B0h, C01);
    C10 = mfma_bf16(B0h, A0h, C10); C10 = mfma_bf16(B0h, A0l, C10); C10 = mfma_bf16(B0l, A0h, C10);
    C11 = mfma_bf16(B0h, B0h, C11); C11 = mfma_bf16(B0h, B0l, C11); C11 = mfma_bf16(B0l, B0h, C11);
    // ks1
    C00 = mfma_bf16(A1h, A1h, C00); C00 = mfma_bf16(A1h, A1l, C00); C00 = mfma_bf16(A1l, A1h, C00);
    C01 = mfma_bf16(A1h, B1h, C01); C01 = mfma_bf16(A1h, B1l, C01); C01 = mfma_bf16(A1l, B1h, C01);
    C10 = mfma_bf16(B1h, A1h, C10); C10 = mfma_bf16(B1h, A1l, C10); C10 = mfma_bf16(B1l, A1h, C10);
    C11 = mfma_bf16(B1h, B1h, C11); C11 = mfma_bf16(B1h, B1l, C11); C11 = mfma_bf16(B1l, B1h, C11);
  }

  // ---- means + correction: Cov = Craw/256 - mx mx^T (in-place) ----
  macc0 += __shfl_xor(macc0, 32);
  macc1 += __shfl_xor(macc1, 32);
  const float mx0 = macc0 * (1.f / 256.f);   // channel col
  const float mx1 = macc1 * (1.f / 256.f);   // channel 32+col
#pragma unroll
  for (int m = 0; m < 16; ++m) {
    const int r = (m & 3) + 8 * (m >> 2) + 4 * half;
    const float mr0 = __shfl(mx0, r);
    const float mr1 = __shfl(mx1, r);
    C00[m] = C00[m] * (1.f / 256.f) - mr0 * mx0;
    C01[m] = C01[m] * (1.f / 256.f) - mr0 * mx1;
    C10[m] = C10[m] * (1.f / 256.f) - mr1 * mx0;
    C11[m] = C11[m] * (1.f / 256.f) - mr1 * mx1;
  }

  // ---- sandwich: Z = Cov*W (Z0 rows 0-31, Z1 rows 32-63), Y = Z^T*W ----
  short8 wh0, wl0, wh1, wl1, wh2, wl2, wh3, wl3;
  loadWfrag(W, 0, half, col, wh0, wl0);
  loadWfrag(W, 1, half, col, wh1, wl1);
  f32x16 Z0 = zero16();
  {
    float t[16];
#pragma unroll
    for (int m = 0; m < 16; ++m) t[m] = C00[m];
    short8 h0, l0, h1, l1; c2frags(t, h0, l0, h1, l1);    // A -> C00
    Z0 = mfma_bf16(h0, wh0, Z0); Z0 = mfma_bf16(h0, wl0, Z0); Z0 = mfma_bf16(l0, wh0, Z0);
    Z0 = mfma_bf16(h1, wh1, Z0); Z0 = mfma_bf16(h1, wl1, Z0); Z0 = mfma_bf16(l1, wh1, Z0);
  }
  f32x16 Z1 = zero16();
  {
    float t[16];
#pragma unroll
    for (int m = 0; m < 16; ++m) t[m] = C01[m];
    short8 h0, l0, h1, l1; c2frags(t, h0, l0, h1, l1);    // A -> C01^T = C10
    Z1 = mfma_bf16(h0, wh0, Z1); Z1 = mfma_bf16(h0, wl0, Z1); Z1 = mfma_bf16(l0, wh0, Z1);
    Z1 = mfma_bf16(h1, wh1, Z1); Z1 = mfma_bf16(h1, wl1, Z1); Z1 = mfma_bf16(l1, wh1, Z1);
  }
  loadWfrag(W, 2, half, col, wh2, wl2);
  loadWfrag(W, 3, half, col, wh3, wl3);
  {
    float t[16];
#pragma unroll
    for (int m = 0; m < 16; ++m) t[m] = C10[m];
    short8 h0, l0, h1, l1; c2frags(t, h0, l0, h1, l1);    // A -> C10^T = C01
    Z0 = mfma_bf16(h0, wh2, Z0); Z0 = mfma_bf16(h0, wl2, Z0); Z0 = mfma_bf16(l0, wh2, Z0);
    Z0 = mfma_bf16(h1, wh3, Z0); Z0 = mfma_bf16(h1, wl3, Z0); Z0 = mfma_bf16(l1, wh3, Z0);
  }
  {
    float t[16];
#pragma unroll
    for (int m = 0; m < 16; ++m) t[m] = C11[m];
    short8 h0, l0, h1, l1; c2frags(t, h0, l0, h1, l1);    // A -> C11
    Z1 = mfma_bf16(h0, wh2, Z1); Z1 = mfma_bf16(h0, wl2, Z1); Z1 = mfma_bf16(l0, wh2, Z1);
    Z1 = mfma_bf16(h1, wh3, Z1); Z1 = mfma_bf16(h1, wl3, Z1); Z1 = mfma_bf16(l1, wh3, Z1);
  }
  // Y = Z^T * W  (K = 64 channel rows of Z)
  f32x16 Ya = zero16();
  {
    float t[16];
#pragma unroll
    for (int m = 0; m < 16; ++m) t[m] = Z0[m];
    short8 h0, l0, h1, l1; c2frags(t, h0, l0, h1, l1);    // A -> Z0^T
    Ya = mfma_bf16(h0, wh0, Ya); Ya = mfma_bf16(h0, wl0, Ya); Ya = mfma_bf16(l0, wh0, Ya);
    Ya = mfma_bf16(h1, wh1, Ya); Ya = mfma_bf16(h1, wl1, Ya); Ya = mfma_bf16(l1, wh1, Ya);
  }
  {
    float t[16];
#pragma unroll
    for (int m = 0; m < 16; ++m) t[m] = Z1[m];
    short8 h0, l0, h1, l1; c2frags(t, h0, l0, h1, l1);    // A -> Z1^T
    Ya = mfma_bf16(h0, wh2, Ya); Ya = mfma_bf16(h0, wl2, Ya); Ya = mfma_bf16(l0, wh2, Ya);
    Ya = mfma_bf16(h1, wh3, Ya); Ya = mfma_bf16(h1, wl3, Ya); Ya = mfma_bf16(l1, wh3, Ya);
  }

  // ---- phase 2: Chebyshev log on [0.25, 2.25]: p=1.25, q=1, r=-0.5, c0=0 ----
  float Tc[16], Tp[16], G[16];
#pragma unroll
  for (int m = 0; m < 16; ++m) {
    const int r = (m & 3) + 8 * (m >> 2) + 4 * half;
    const float dg = (r == col) ? 1.f : 0.f;
    const float yn = Ya[m] - 1.25f * dg;      // u = (Y - p I)/q, q=1
    Tc[m] = yn; Tp[m] = dg;
    G[m] = yn;                                 // c1 = -2r = 1.0, c0 = 0
  }
  short8 ah0, al0, ah1, al1;
  c2frags(Tc, ah0, al0, ah1, al1);             // A -> Yhat (symmetric)

  constexpr float CK[NCH + 1] = {
      0.f, 1.f, -0.25f, 0.083333336f, -0.03125f, 0.0125f, -0.0052083335f,
      0.0022321427f, -0.0009765625f, 0.00043402778f, -0.0001953125f,
      0.000088778407f};
#pragma unroll
  for (int k = 2; k <= NCH; ++k) {
    short8 bh0, bl0, bh1, bl1;
    c2frags(Tc, bh0, bl0, bh1, bl1);
    f32x16 P1 = zero16(), P2 = zero16();
    P1 = mfma_bf16(ah0, bh0, P1); P1 = mfma_bf16(ah0, bl0, P1); P1 = mfma_bf16(al0, bh0, P1);
    P2 = mfma_bf16(ah1, bh1, P2); P2 = mfma_bf16(ah1, bl1, P2); P2 = mfma_bf16(al1, bh1, P2);
    const float ck = CK[k];
#pragma unroll
    for (int m = 0; m < 16; ++m) {
      const float tn = 2.f * (P1[m] + P2[m]) - Tp[m];
      Tp[m] = Tc[m]; Tc[m] = tn;
      G[m] = fmaf(ck, tn, G[m]);
    }
  }

  // ---- logits + log_softmax ----
  float S[4];
#pragma unroll
  for (int o = 0; o < 4; ++o) {
    float s = 0.f;
#pragma unroll
    for (int m = 0; m < 16; ++m) {
      const int r = (m & 3) + 8 * (m >> 2) + 4 * half;
      s = fmaf(Wc[o * 1024 + r * 32 + col], G[m], s);
    }
    S[o] = s;
  }
#pragma unroll
  for (int off = 32; off >= 1; off >>= 1) {
    S[0] += __shfl_xor(S[0], off);
    S[1] += __shfl_xor(S[1], off);
    S[2] += __shfl_xor(S[2], off);
    S[3] += __shfl_xor(S[3], off);
  }
  if (l == 0) {
    const float lg0 = S[0] + bcv[0];
    const float lg1 = S[1] + bcv[1];
    const float lg2 = S[2] + bcv[2];
    const float lg3 = S[3] + bcv[3];
    const float mx = fmaxf(fmaxf(lg0, lg1), fmaxf(lg2, lg3));
    const float se = expf(lg0 - mx) + expf(lg1 - mx) +
                     expf(lg2 - mx) + expf(lg3 - mx);
    const float lse = mx + logf(se);
    *(float4*)&out[(size_t)b * 4] =
        make_float4(lg0 - lse, lg1 - lse, lg2 - lse, lg3 - lse);
  }
}

extern "C" void kernel_launch(void* const* d_in, const int* in_sizes, int n_in,
                              void* d_out, int out_size, void* d_ws, size_t ws_size,
                              hipStream_t stream)
{
  const float* x  = (const float*)d_in[0];
  const float* W  = (const float*)d_in[1];
  const float* Wc = (const float*)d_in[2];
  const float* bc = (const float*)d_in[3];
  float* out = (float*)d_out;
  (void)d_ws; (void)ws_size;

  const int nB = in_sizes[0] / (64 * 256);   // 4096
  const int blocks = (nB + 3) / 4;

  spd_fused<<<blocks, 256, 0, stream>>>(x, W, Wc, bc, out, nB);
}